// Round 1
// baseline (246.723 us; speedup 1.0000x reference)
//
#include <hip/hip_runtime.h>
#include <hip/hip_bf16.h>

// Problem constants
#define BB 2
#define TT 2048
#define DD 1024
#define NN 16
#define RR 64          // DT_RANK
#define MM (BB*TT)     // 4096 rows
#define KDIM DD        // 1024
#define CHUNK 128
#define NCHUNK (TT/CHUNK)  // 16

// Workspace layout (in floats)
#define BT_OFF 0                      // Bt: MM*NN      = 65536
#define CT_OFF 65536                  // Ct: MM*NN      = 65536
#define R1_OFF 131072                 // R1: MM*RR      = 262144
#define DT_OFF 393216                 // dt: MM*DD      = 4194304
#define P_OFF  4587520                // P : NCHUNK*BB*DD*NN = 524288
#define S_OFF  5111808                // S : same       = 524288
// total 5636096 floats = 22.5 MB

__device__ __forceinline__ float softplus_f(float z) {
    // stable softplus: max(z,0) + log1p(exp(-|z|))
    return fmaxf(z, 0.0f) + log1pf(expf(-fabsf(z)));
}

// ---------------------------------------------------------------------------
// Kernel 1: combined projection  [Bt | Ct | R1] = x @ [W_B; W_C; W_dt1]^T
// M=4096, K=1024, Ncols=96.  K-split x4 with fp32 atomics (outputs pre-zeroed).
// grid (64 rowtiles, 4 ksplit), block 256. Tile: 64 rows x 96 cols,
// thread-tile 4 rows x 6 cols.
// ---------------------------------------------------------------------------
__global__ __launch_bounds__(256) void k_proj96(
    const float* __restrict__ x, const float* __restrict__ W_B,
    const float* __restrict__ W_C, const float* __restrict__ W_dt1,
    float* __restrict__ Bt, float* __restrict__ Ct, float* __restrict__ R1)
{
    __shared__ float xs[16][68];   // [k][row], stride 68 -> 16B-aligned rows4
    __shared__ float wsT[16][97];  // [k][col], stride 97 breaks bank aliasing

    const int tid = threadIdx.x;
    const int r0 = blockIdx.x * 64;
    const int kbase = blockIdx.y * 256;
    const int tx = tid & 15;   // col group: cols tx + 16*j
    const int ty = tid >> 4;   // row group: rows ty*4 .. ty*4+3

    float acc[4][6];
    #pragma unroll
    for (int i = 0; i < 4; i++)
        #pragma unroll
        for (int j = 0; j < 6; j++) acc[i][j] = 0.0f;

    for (int kc = 0; kc < 256; kc += 16) {
        // stage x tile: 64 rows x 16 k (transposed into xs[k][row])
        {
            const int row = tid >> 2;
            const int kq = (tid & 3) * 4;
            float4 v = *(const float4*)(x + (size_t)(r0 + row) * KDIM + kbase + kc + kq);
            xs[kq + 0][row] = v.x; xs[kq + 1][row] = v.y;
            xs[kq + 2][row] = v.z; xs[kq + 3][row] = v.w;
        }
        // stage W tile: 96 cols x 16 k (transposed into wsT[k][col])
        #pragma unroll
        for (int i = 0; i < 6; i++) {
            const int idx = i * 256 + tid;
            const int c = idx >> 4;
            const int kk = idx & 15;
            const float* wrow; int cc;
            if (c < 16)      { wrow = W_B;   cc = c; }
            else if (c < 32) { wrow = W_C;   cc = c - 16; }
            else             { wrow = W_dt1; cc = c - 32; }
            wsT[kk][c] = wrow[(size_t)cc * KDIM + kbase + kc + kk];
        }
        __syncthreads();
        #pragma unroll
        for (int kk = 0; kk < 16; kk++) {
            const float a0 = xs[kk][ty * 4 + 0];
            const float a1 = xs[kk][ty * 4 + 1];
            const float a2 = xs[kk][ty * 4 + 2];
            const float a3 = xs[kk][ty * 4 + 3];
            #pragma unroll
            for (int j = 0; j < 6; j++) {
                const float b = wsT[kk][tx + j * 16];
                acc[0][j] = fmaf(a0, b, acc[0][j]);
                acc[1][j] = fmaf(a1, b, acc[1][j]);
                acc[2][j] = fmaf(a2, b, acc[2][j]);
                acc[3][j] = fmaf(a3, b, acc[3][j]);
            }
        }
        __syncthreads();
    }

    #pragma unroll
    for (int i = 0; i < 4; i++) {
        const int r = r0 + ty * 4 + i;
        #pragma unroll
        for (int j = 0; j < 6; j++) {
            const int c = tx + j * 16;   // branch resolves statically per j
            const float v = acc[i][j];
            if (c < 16)      atomicAdd(&Bt[r * NN + c], v);
            else if (c < 32) atomicAdd(&Ct[r * NN + (c - 16)], v);
            else             atomicAdd(&R1[r * RR + (c - 32)], v);
        }
    }
}

// ---------------------------------------------------------------------------
// Kernel 2: dt = softplus(R1 @ W_dt2^T + b_dt2).  M=4096, N=1024, K=64.
// grid (256 rowtiles, 4 dtiles), block 256. Tile 16 rows x 256 d,
// thread: 1 row x 16 d (as 4 float4).
// ---------------------------------------------------------------------------
__global__ __launch_bounds__(256) void k_dtproj(
    const float* __restrict__ R1, const float* __restrict__ W_dt2,
    const float* __restrict__ b_dt2, float* __restrict__ dt)
{
    __shared__ float r1s[16][65];
    __shared__ float wsT[64][256];  // [k][d_local]

    const int tid = threadIdx.x;
    const int r0 = blockIdx.x * 16;
    const int d0 = blockIdx.y * 256;

    // stage R1 tile: 16 rows x 64 k
    {
        const int row = tid >> 4;
        const int kq = (tid & 15) * 4;
        float4 v = *(const float4*)(R1 + (size_t)(r0 + row) * RR + kq);
        r1s[row][kq + 0] = v.x; r1s[row][kq + 1] = v.y;
        r1s[row][kq + 2] = v.z; r1s[row][kq + 3] = v.w;
    }
    // stage W_dt2 tile transposed: 256 d x 64 k -> wsT[k][dl]
    {
        const float* src = W_dt2 + (size_t)(d0 + tid) * RR;
        #pragma unroll
        for (int kq = 0; kq < 64; kq += 4) {
            float4 v = *(const float4*)(src + kq);
            wsT[kq + 0][tid] = v.x; wsT[kq + 1][tid] = v.y;
            wsT[kq + 2][tid] = v.z; wsT[kq + 3][tid] = v.w;
        }
    }
    __syncthreads();

    const int r = tid & 15;    // row within tile
    const int dg = tid >> 4;   // d-group: cols dg*16 .. dg*16+15

    float4 acc[4];
    #pragma unroll
    for (int q = 0; q < 4; q++) acc[q] = make_float4(0.f, 0.f, 0.f, 0.f);

    #pragma unroll 4
    for (int k = 0; k < 64; k++) {
        const float a = r1s[r][k];
        #pragma unroll
        for (int q = 0; q < 4; q++) {
            float4 bv = *(const float4*)&wsT[k][dg * 16 + q * 4];
            acc[q].x = fmaf(a, bv.x, acc[q].x);
            acc[q].y = fmaf(a, bv.y, acc[q].y);
            acc[q].z = fmaf(a, bv.z, acc[q].z);
            acc[q].w = fmaf(a, bv.w, acc[q].w);
        }
    }

    float* out = dt + (size_t)(r0 + r) * DD + d0 + dg * 16;
    const float* bb = b_dt2 + d0 + dg * 16;
    #pragma unroll
    for (int q = 0; q < 4; q++) {
        float4 bias = *(const float4*)(bb + q * 4);
        float4 o;
        o.x = softplus_f(acc[q].x + bias.x);
        o.y = softplus_f(acc[q].y + bias.y);
        o.z = softplus_f(acc[q].z + bias.z);
        o.w = softplus_f(acc[q].w + bias.w);
        *(float4*)(out + q * 4) = o;
    }
}

// ---------------------------------------------------------------------------
// Kernel 3: chunked scan pass 1 — per (b,d,n,chunk) compute
//   P = prod_t a_t,  S = local scan from h=0.
// grid (DD/16, NCHUNK, BB), block 256 (16 d x 16 n).
// ---------------------------------------------------------------------------
__global__ __launch_bounds__(256) void k_scan1(
    const float* __restrict__ x, const float* __restrict__ dt,
    const float* __restrict__ Bt, const float* __restrict__ log_A,
    float* __restrict__ P, float* __restrict__ S)
{
    const int tid = threadIdx.x;
    const int n = tid & 15;
    const int dl = tid >> 4;
    const int d = blockIdx.x * 16 + dl;
    const int c = blockIdx.y;
    const int b = blockIdx.z;

    const float A = -__expf(log_A[d * NN + n]);
    const float rA = 1.0f / (A + 1e-8f);

    float Pv = 1.0f, Sv = 0.0f;
    const int base = b * TT + c * CHUNK;
    const float* dtp = dt + (size_t)base * DD + d;
    const float* xp  = x  + (size_t)base * DD + d;
    const float* btp = Bt + (size_t)base * NN + n;

    #pragma unroll 4
    for (int t = 0; t < CHUNK; t++) {
        const float dtv = dtp[(size_t)t * DD];
        const float xv  = xp[(size_t)t * DD];
        const float btv = btp[(size_t)t * NN];
        const float a = __expf(dtv * A);
        const float bv = (a - 1.0f) * rA * xv * btv;
        Pv *= a;
        Sv = fmaf(a, Sv, bv);
    }
    const int oidx = ((c * BB + b) * DD + d) * NN + n;
    P[oidx] = Pv;
    S[oidx] = Sv;
}

// ---------------------------------------------------------------------------
// Kernel 4: chunked scan pass 2 — recombine chunk transitions to get h_init
// (cheap: <=15 fma), then replay chunk with true h, reduce over n, write y.
// grid (DD/16, NCHUNK, BB), block 256 (16 d x 16 n).
// ---------------------------------------------------------------------------
__global__ __launch_bounds__(256) void k_scan2(
    const float* __restrict__ x, const float* __restrict__ dt,
    const float* __restrict__ Bt, const float* __restrict__ Ct,
    const float* __restrict__ log_A, const float* __restrict__ D_skip,
    const float* __restrict__ P, const float* __restrict__ S,
    float* __restrict__ y)
{
    const int tid = threadIdx.x;
    const int n = tid & 15;
    const int dl = tid >> 4;
    const int d = blockIdx.x * 16 + dl;
    const int c = blockIdx.y;
    const int b = blockIdx.z;

    const float A = -__expf(log_A[d * NN + n]);
    const float rA = 1.0f / (A + 1e-8f);

    // h_init for this chunk from previous chunk transitions
    float h = 0.0f;
    for (int cc = 0; cc < c; cc++) {
        const int idx = ((cc * BB + b) * DD + d) * NN + n;
        h = fmaf(P[idx], h, S[idx]);
    }

    const float dsk = D_skip[d];
    const int base = b * TT + c * CHUNK;
    const float* dtp = dt + (size_t)base * DD + d;
    const float* xp  = x  + (size_t)base * DD + d;
    const float* btp = Bt + (size_t)base * NN + n;
    const float* ctp = Ct + (size_t)base * NN + n;
    float* yp = y + (size_t)base * DD + d;

    #pragma unroll 4
    for (int t = 0; t < CHUNK; t++) {
        const float dtv = dtp[(size_t)t * DD];
        const float xv  = xp[(size_t)t * DD];
        const float btv = btp[(size_t)t * NN];
        const float ctv = ctp[(size_t)t * NN];
        const float a = __expf(dtv * A);
        const float bv = (a - 1.0f) * rA * xv * btv;
        h = fmaf(a, h, bv);
        float part = h * ctv;
        part += __shfl_xor(part, 1);
        part += __shfl_xor(part, 2);
        part += __shfl_xor(part, 4);
        part += __shfl_xor(part, 8);
        if (n == 0) yp[(size_t)t * DD] = fmaf(dsk, xv, part);
    }
}

// ---------------------------------------------------------------------------
extern "C" void kernel_launch(void* const* d_in, const int* in_sizes, int n_in,
                              void* d_out, int out_size, void* d_ws, size_t ws_size,
                              hipStream_t stream)
{
    const float* x      = (const float*)d_in[0];
    const float* W_B    = (const float*)d_in[1];
    const float* W_C    = (const float*)d_in[2];
    const float* W_dt1  = (const float*)d_in[3];
    const float* W_dt2  = (const float*)d_in[4];
    const float* b_dt2  = (const float*)d_in[5];
    const float* log_A  = (const float*)d_in[6];
    const float* D_skip = (const float*)d_in[7];
    float* y = (float*)d_out;

    float* ws = (float*)d_ws;
    float* Bt = ws + BT_OFF;
    float* Ct = ws + CT_OFF;
    float* R1 = ws + R1_OFF;
    float* dt = ws + DT_OFF;
    float* P  = ws + P_OFF;
    float* S  = ws + S_OFF;

    // zero the atomic-accumulated projection outputs (Bt|Ct|R1 contiguous)
    hipMemsetAsync(d_ws, 0, (size_t)DT_OFF * sizeof(float), stream);

    k_proj96<<<dim3(MM / 64, 4), 256, 0, stream>>>(x, W_B, W_C, W_dt1, Bt, Ct, R1);
    k_dtproj<<<dim3(MM / 16, DD / 256), 256, 0, stream>>>(R1, W_dt2, b_dt2, dt);
    k_scan1<<<dim3(DD / 16, NCHUNK, BB), 256, 0, stream>>>(x, dt, Bt, log_A, P, S);
    k_scan2<<<dim3(DD / 16, NCHUNK, BB), 256, 0, stream>>>(x, dt, Bt, Ct, log_A, D_skip, P, S, y);
}

// Round 2
// 223.920 us; speedup vs baseline: 1.1018x; 1.1018x over previous
//
#include <hip/hip_runtime.h>
#include <hip/hip_bf16.h>

// Problem constants
#define BB 2
#define TT 2048
#define DD 1024
#define NN 16
#define RR 64          // DT_RANK
#define MM (BB*TT)     // 4096 rows
#define KDIM DD        // 1024
#define CHUNK 128
#define NCHUNK (TT/CHUNK)  // 16
#define DTILE 16           // d-columns per scan block

// Workspace layout (in floats)
#define BT_OFF 0                      // Bt: MM*NN      = 65536
#define CT_OFF 65536                  // Ct: MM*NN      = 65536
#define R1_OFF 131072                 // R1: MM*RR      = 262144
#define DT_OFF 393216                 // dt: MM*DD      = 4194304
#define P_OFF  4587520                // P : NCHUNK*BB*DD*NN = 524288
#define S_OFF  5111808                // S : same       = 524288
// total 5636096 floats = 22.5 MB

__device__ __forceinline__ float softplus_f(float z) {
    return fmaxf(z, 0.0f) + log1pf(expf(-fabsf(z)));
}

// ---------------------------------------------------------------------------
// Kernel 1: combined projection  [Bt | Ct | R1] = x @ [W_B; W_C; W_dt1]^T
// (unchanged this round — will tune after counters show its cost)
// ---------------------------------------------------------------------------
__global__ __launch_bounds__(256) void k_proj96(
    const float* __restrict__ x, const float* __restrict__ W_B,
    const float* __restrict__ W_C, const float* __restrict__ W_dt1,
    float* __restrict__ Bt, float* __restrict__ Ct, float* __restrict__ R1)
{
    __shared__ float xs[16][68];
    __shared__ float wsT[16][97];

    const int tid = threadIdx.x;
    const int r0 = blockIdx.x * 64;
    const int kbase = blockIdx.y * 256;
    const int tx = tid & 15;
    const int ty = tid >> 4;

    float acc[4][6];
    #pragma unroll
    for (int i = 0; i < 4; i++)
        #pragma unroll
        for (int j = 0; j < 6; j++) acc[i][j] = 0.0f;

    for (int kc = 0; kc < 256; kc += 16) {
        {
            const int row = tid >> 2;
            const int kq = (tid & 3) * 4;
            float4 v = *(const float4*)(x + (size_t)(r0 + row) * KDIM + kbase + kc + kq);
            xs[kq + 0][row] = v.x; xs[kq + 1][row] = v.y;
            xs[kq + 2][row] = v.z; xs[kq + 3][row] = v.w;
        }
        #pragma unroll
        for (int i = 0; i < 6; i++) {
            const int idx = i * 256 + tid;
            const int c = idx >> 4;
            const int kk = idx & 15;
            const float* wrow; int cc;
            if (c < 16)      { wrow = W_B;   cc = c; }
            else if (c < 32) { wrow = W_C;   cc = c - 16; }
            else             { wrow = W_dt1; cc = c - 32; }
            wsT[kk][c] = wrow[(size_t)cc * KDIM + kbase + kc + kk];
        }
        __syncthreads();
        #pragma unroll
        for (int kk = 0; kk < 16; kk++) {
            const float a0 = xs[kk][ty * 4 + 0];
            const float a1 = xs[kk][ty * 4 + 1];
            const float a2 = xs[kk][ty * 4 + 2];
            const float a3 = xs[kk][ty * 4 + 3];
            #pragma unroll
            for (int j = 0; j < 6; j++) {
                const float b = wsT[kk][tx + j * 16];
                acc[0][j] = fmaf(a0, b, acc[0][j]);
                acc[1][j] = fmaf(a1, b, acc[1][j]);
                acc[2][j] = fmaf(a2, b, acc[2][j]);
                acc[3][j] = fmaf(a3, b, acc[3][j]);
            }
        }
        __syncthreads();
    }

    #pragma unroll
    for (int i = 0; i < 4; i++) {
        const int r = r0 + ty * 4 + i;
        #pragma unroll
        for (int j = 0; j < 6; j++) {
            const int c = tx + j * 16;
            const float v = acc[i][j];
            if (c < 16)      atomicAdd(&Bt[r * NN + c], v);
            else if (c < 32) atomicAdd(&Ct[r * NN + (c - 16)], v);
            else             atomicAdd(&R1[r * RR + (c - 32)], v);
        }
    }
}

// ---------------------------------------------------------------------------
// Kernel 2: dt = softplus(R1 @ W_dt2^T + b_dt2).  (unchanged this round)
// ---------------------------------------------------------------------------
__global__ __launch_bounds__(256) void k_dtproj(
    const float* __restrict__ R1, const float* __restrict__ W_dt2,
    const float* __restrict__ b_dt2, float* __restrict__ dt)
{
    __shared__ float r1s[16][65];
    __shared__ float wsT[64][256];

    const int tid = threadIdx.x;
    const int r0 = blockIdx.x * 16;
    const int d0 = blockIdx.y * 256;

    {
        const int row = tid >> 4;
        const int kq = (tid & 15) * 4;
        float4 v = *(const float4*)(R1 + (size_t)(r0 + row) * RR + kq);
        r1s[row][kq + 0] = v.x; r1s[row][kq + 1] = v.y;
        r1s[row][kq + 2] = v.z; r1s[row][kq + 3] = v.w;
    }
    {
        const float* src = W_dt2 + (size_t)(d0 + tid) * RR;
        #pragma unroll
        for (int kq = 0; kq < 64; kq += 4) {
            float4 v = *(const float4*)(src + kq);
            wsT[kq + 0][tid] = v.x; wsT[kq + 1][tid] = v.y;
            wsT[kq + 2][tid] = v.z; wsT[kq + 3][tid] = v.w;
        }
    }
    __syncthreads();

    const int r = tid & 15;
    const int dg = tid >> 4;

    float4 acc[4];
    #pragma unroll
    for (int q = 0; q < 4; q++) acc[q] = make_float4(0.f, 0.f, 0.f, 0.f);

    #pragma unroll 4
    for (int k = 0; k < 64; k++) {
        const float a = r1s[r][k];
        #pragma unroll
        for (int q = 0; q < 4; q++) {
            float4 bv = *(const float4*)&wsT[k][dg * 16 + q * 4];
            acc[q].x = fmaf(a, bv.x, acc[q].x);
            acc[q].y = fmaf(a, bv.y, acc[q].y);
            acc[q].z = fmaf(a, bv.z, acc[q].z);
            acc[q].w = fmaf(a, bv.w, acc[q].w);
        }
    }

    float* out = dt + (size_t)(r0 + r) * DD + d0 + dg * 16;
    const float* bb = b_dt2 + d0 + dg * 16;
    #pragma unroll
    for (int q = 0; q < 4; q++) {
        float4 bias = *(const float4*)(bb + q * 4);
        float4 o;
        o.x = softplus_f(acc[q].x + bias.x);
        o.y = softplus_f(acc[q].y + bias.y);
        o.z = softplus_f(acc[q].z + bias.z);
        o.w = softplus_f(acc[q].w + bias.w);
        *(float4*)(out + q * 4) = o;
    }
}

// ---------------------------------------------------------------------------
// Scan kernels, LDS-staged.
// Block = 128 threads: dl = tid>>3 in [0,16)  (d = d0+dl),
//                      ng = tid&7            (n pair: 2*ng, 2*ng+1).
// Each block: (batch b, chunk c, 16 d's). Tiles staged via coalesced float4.
// Inner loop reads LDS only: dt/x broadcast 8-way across ng (free),
// Bt/Ct read as float2 across 16 banks (broadcast across dl).
// ---------------------------------------------------------------------------
__global__ __launch_bounds__(128) void k_scan1(
    const float* __restrict__ x, const float* __restrict__ dt,
    const float* __restrict__ Bt, const float* __restrict__ log_A,
    float* __restrict__ P, float* __restrict__ S)
{
    __shared__ float dt_s[CHUNK][DTILE];
    __shared__ float x_s[CHUNK][DTILE];
    __shared__ float bt_s[CHUNK][NN];

    const int tid = threadIdx.x;
    const int dl = tid >> 3;
    const int ng = tid & 7;
    const int d0 = blockIdx.x * DTILE;
    const int d = d0 + dl;
    const int c = blockIdx.y;
    const int b = blockIdx.z;
    const int n0 = ng * 2;
    const int base = b * TT + c * CHUNK;

    // per-thread constants (independent of LDS)
    const float2 lg = *(const float2*)(log_A + d * NN + n0);
    const float A0 = -__expf(lg.x);
    const float A1 = -__expf(lg.y);
    const float rA0 = 1.0f / (A0 + 1e-8f);
    const float rA1 = 1.0f / (A1 + 1e-8f);

    // stage tiles: 512 float4 per (dt,x), 512 per bt -> 4 each per thread
    {
        const float* gdt = dt + (size_t)base * DD + d0;
        const float* gx  = x  + (size_t)base * DD + d0;
        const float* gbt = Bt + (size_t)base * NN;
        #pragma unroll
        for (int k = 0; k < 4; k++) {
            const int f = tid + k * 128;        // 0..511
            const int t = f >> 2;
            const int j = (f & 3) * 4;
            *(float4*)&dt_s[t][j] = *(const float4*)(gdt + (size_t)t * DD + j);
            *(float4*)&x_s[t][j]  = *(const float4*)(gx  + (size_t)t * DD + j);
            *(float4*)&bt_s[t][j] = *(const float4*)(gbt + (size_t)t * NN + j);
        }
    }
    __syncthreads();

    float P0 = 1.0f, P1 = 1.0f, S0 = 0.0f, S1 = 0.0f;
    #pragma unroll 8
    for (int t = 0; t < CHUNK; t++) {
        const float dtv = dt_s[t][dl];
        const float xv  = x_s[t][dl];
        const float2 bt2 = *(const float2*)&bt_s[t][n0];
        const float a0 = __expf(dtv * A0);
        const float a1 = __expf(dtv * A1);
        const float bv0 = (a0 - 1.0f) * rA0 * xv * bt2.x;
        const float bv1 = (a1 - 1.0f) * rA1 * xv * bt2.y;
        P0 *= a0; P1 *= a1;
        S0 = fmaf(a0, S0, bv0);
        S1 = fmaf(a1, S1, bv1);
    }
    const int oidx = ((c * BB + b) * DD + d) * NN + n0;
    *(float2*)(P + oidx) = make_float2(P0, P1);
    *(float2*)(S + oidx) = make_float2(S0, S1);
}

__global__ __launch_bounds__(128) void k_scan2(
    const float* __restrict__ x, const float* __restrict__ dt,
    const float* __restrict__ Bt, const float* __restrict__ Ct,
    const float* __restrict__ log_A, const float* __restrict__ D_skip,
    const float* __restrict__ P, const float* __restrict__ S,
    float* __restrict__ y)
{
    __shared__ float dt_s[CHUNK][DTILE];
    __shared__ float x_s[CHUNK][DTILE];
    __shared__ float bt_s[CHUNK][NN];
    __shared__ float ct_s[CHUNK][NN];

    const int tid = threadIdx.x;
    const int dl = tid >> 3;
    const int ng = tid & 7;
    const int d0 = blockIdx.x * DTILE;
    const int d = d0 + dl;
    const int c = blockIdx.y;
    const int b = blockIdx.z;
    const int n0 = ng * 2;
    const int base = b * TT + c * CHUNK;

    const float2 lg = *(const float2*)(log_A + d * NN + n0);
    const float A0 = -__expf(lg.x);
    const float A1 = -__expf(lg.y);
    const float rA0 = 1.0f / (A0 + 1e-8f);
    const float rA1 = 1.0f / (A1 + 1e-8f);
    const float dsk = D_skip[d];

    // h_init from previous chunk transitions (global loads, pre-sync overlap)
    float h0 = 0.0f, h1 = 0.0f;
    for (int cc = 0; cc < c; cc++) {
        const int idx = ((cc * BB + b) * DD + d) * NN + n0;
        const float2 Pv = *(const float2*)(P + idx);
        const float2 Sv = *(const float2*)(S + idx);
        h0 = fmaf(Pv.x, h0, Sv.x);
        h1 = fmaf(Pv.y, h1, Sv.y);
    }

    {
        const float* gdt = dt + (size_t)base * DD + d0;
        const float* gx  = x  + (size_t)base * DD + d0;
        const float* gbt = Bt + (size_t)base * NN;
        const float* gct = Ct + (size_t)base * NN;
        #pragma unroll
        for (int k = 0; k < 4; k++) {
            const int f = tid + k * 128;
            const int t = f >> 2;
            const int j = (f & 3) * 4;
            *(float4*)&dt_s[t][j] = *(const float4*)(gdt + (size_t)t * DD + j);
            *(float4*)&x_s[t][j]  = *(const float4*)(gx  + (size_t)t * DD + j);
            *(float4*)&bt_s[t][j] = *(const float4*)(gbt + (size_t)t * NN + j);
            *(float4*)&ct_s[t][j] = *(const float4*)(gct + (size_t)t * NN + j);
        }
    }
    __syncthreads();

    float* yp = y + (size_t)base * DD + d;
    #pragma unroll 8
    for (int t = 0; t < CHUNK; t++) {
        const float dtv = dt_s[t][dl];
        const float xv  = x_s[t][dl];
        const float2 bt2 = *(const float2*)&bt_s[t][n0];
        const float2 ct2 = *(const float2*)&ct_s[t][n0];
        const float a0 = __expf(dtv * A0);
        const float a1 = __expf(dtv * A1);
        const float bv0 = (a0 - 1.0f) * rA0 * xv * bt2.x;
        const float bv1 = (a1 - 1.0f) * rA1 * xv * bt2.y;
        h0 = fmaf(a0, h0, bv0);
        h1 = fmaf(a1, h1, bv1);
        float part = fmaf(h1, ct2.y, h0 * ct2.x);
        part += __shfl_xor(part, 1);
        part += __shfl_xor(part, 2);
        part += __shfl_xor(part, 4);
        if (ng == 0) yp[(size_t)t * DD] = fmaf(dsk, xv, part);
    }
}

// ---------------------------------------------------------------------------
extern "C" void kernel_launch(void* const* d_in, const int* in_sizes, int n_in,
                              void* d_out, int out_size, void* d_ws, size_t ws_size,
                              hipStream_t stream)
{
    const float* x      = (const float*)d_in[0];
    const float* W_B    = (const float*)d_in[1];
    const float* W_C    = (const float*)d_in[2];
    const float* W_dt1  = (const float*)d_in[3];
    const float* W_dt2  = (const float*)d_in[4];
    const float* b_dt2  = (const float*)d_in[5];
    const float* log_A  = (const float*)d_in[6];
    const float* D_skip = (const float*)d_in[7];
    float* y = (float*)d_out;

    float* ws = (float*)d_ws;
    float* Bt = ws + BT_OFF;
    float* Ct = ws + CT_OFF;
    float* R1 = ws + R1_OFF;
    float* dt = ws + DT_OFF;
    float* P  = ws + P_OFF;
    float* S  = ws + S_OFF;

    hipMemsetAsync(d_ws, 0, (size_t)DT_OFF * sizeof(float), stream);

    k_proj96<<<dim3(MM / 64, 4), 256, 0, stream>>>(x, W_B, W_C, W_dt1, Bt, Ct, R1);
    k_dtproj<<<dim3(MM / 16, DD / 256), 256, 0, stream>>>(R1, W_dt2, b_dt2, dt);
    k_scan1<<<dim3(DD / DTILE, NCHUNK, BB), 128, 0, stream>>>(x, dt, Bt, log_A, P, S);
    k_scan2<<<dim3(DD / DTILE, NCHUNK, BB), 128, 0, stream>>>(x, dt, Bt, Ct, log_A, D_skip, P, S, y);
}